// Round 1
// baseline (105.343 us; speedup 1.0000x reference)
//
#include <hip/hip_runtime.h>

#define NUM_FIELDS 10
#define FACTOR_DIM 8
#define BATCH      16384
#define INPUT_DIM  188610
#define NPAIRS     45

__device__ __constant__ int c_off[NUM_FIELDS] =
    {0, 100000, 150000, 170000, 180000, 185000, 187000, 188000, 188500, 188600};

// pair p -> (f, g) with f < g, f-major order
__device__ __constant__ int c_pf[NPAIRS] = {
    0,0,0,0,0,0,0,0,0,
    1,1,1,1,1,1,1,1,
    2,2,2,2,2,2,2,
    3,3,3,3,3,3,
    4,4,4,4,4,
    5,5,5,5,
    6,6,6,
    7,7,
    8};
__device__ __constant__ int c_pg[NPAIRS] = {
    1,2,3,4,5,6,7,8,9,
    2,3,4,5,6,7,8,9,
    3,4,5,6,7,8,9,
    4,5,6,7,8,9,
    5,6,7,8,9,
    6,7,8,9,
    7,8,9,
    8,9,
    9};

__global__ __launch_bounds__(256) void ffm_kernel(
    const int* __restrict__ x,       // (B, F) int32
    const float* __restrict__ w,     // (INPUT_DIM,)
    const float* __restrict__ blin,  // scalar
    const float* __restrict__ emb,   // (F, INPUT_DIM, D)
    float* __restrict__ out)         // (B,)
{
    const int gtid   = blockIdx.x * blockDim.x + threadIdx.x;
    const int wave   = gtid >> 6;
    const int lane   = threadIdx.x & 63;
    const int nwaves = (gridDim.x * blockDim.x) >> 6;

    const float bl = *blin;

    // pair mapping for this lane (clamped so all lanes have valid values)
    const int p  = (lane < NPAIRS) ? lane : 0;
    const int pf = c_pf[p];
    const int pg = c_pg[p];
    const int jl = (lane >= NPAIRS && lane < NPAIRS + NUM_FIELDS) ? (lane - NPAIRS) : 0;

    for (int b = wave; b < BATCH; b += nwaves) {
        // lanes 0..9 load this sample's global indices
        int idx = 0;
        if (lane < NUM_FIELDS) idx = x[b * NUM_FIELDS + lane] + c_off[lane];

        // broadcast BEFORE divergence so all source lanes are active
        const int idx_g = __shfl(idx, pg);   // x_off[b, g]
        const int idx_f = __shfl(idx, pf);   // x_off[b, f]
        const int idx_j = __shfl(idx, jl);   // x_off[b, lane-45]

        float val = 0.0f;
        if (lane < NPAIRS) {
            // dot( emb[f, idx_g, :], emb[g, idx_f, :] )
            const float4* pa = reinterpret_cast<const float4*>(
                emb + ((size_t)pf * INPUT_DIM + idx_g) * FACTOR_DIM);
            const float4* pb = reinterpret_cast<const float4*>(
                emb + ((size_t)pg * INPUT_DIM + idx_f) * FACTOR_DIM);
            float4 a0 = pa[0], a1 = pa[1];
            float4 b0 = pb[0], b1 = pb[1];
            val = a0.x * b0.x + a0.y * b0.y + a0.z * b0.z + a0.w * b0.w
                + a1.x * b1.x + a1.y * b1.y + a1.z * b1.z + a1.w * b1.w;
        } else if (lane < NPAIRS + NUM_FIELDS) {
            val = w[idx_j];
        }

        // full-wave (64-lane) butterfly reduction
        #pragma unroll
        for (int m = 1; m < 64; m <<= 1)
            val += __shfl_xor(val, m);

        if (lane == 0) out[b] = val + bl;
    }
}

extern "C" void kernel_launch(void* const* d_in, const int* in_sizes, int n_in,
                              void* d_out, int out_size, void* d_ws, size_t ws_size,
                              hipStream_t stream) {
    const int*   x    = (const int*)d_in[0];
    const float* w    = (const float*)d_in[1];
    const float* blin = (const float*)d_in[2];
    const float* emb  = (const float*)d_in[3];
    float*       out  = (float*)d_out;

    dim3 block(256);
    dim3 grid(2048);   // 8192 waves -> 2 samples/wave, 32 waves/CU
    hipLaunchKernelGGL(ffm_kernel, grid, block, 0, stream, x, w, blin, emb, out);
}

// Round 2
// 103.940 us; speedup vs baseline: 1.0135x; 1.0135x over previous
//
#include <hip/hip_runtime.h>

#define NUM_FIELDS 10
#define FACTOR_DIM 8
#define BATCH      16384
#define INPUT_DIM  188610
#define NPAIRS     45
#define SPW        4   // samples per wave

// offsets replicated 4x so lane (s*10+f) gets field f's offset directly
__device__ __constant__ int c_off40[SPW * NUM_FIELDS] = {
    0, 100000, 150000, 170000, 180000, 185000, 187000, 188000, 188500, 188600,
    0, 100000, 150000, 170000, 180000, 185000, 187000, 188000, 188500, 188600,
    0, 100000, 150000, 170000, 180000, 185000, 187000, 188000, 188500, 188600,
    0, 100000, 150000, 170000, 180000, 185000, 187000, 188000, 188500, 188600};

// pair p -> (f, g) with f < g, f-major order
__device__ __constant__ int c_pf[NPAIRS] = {
    0,0,0,0,0,0,0,0,0,
    1,1,1,1,1,1,1,1,
    2,2,2,2,2,2,2,
    3,3,3,3,3,3,
    4,4,4,4,4,
    5,5,5,5,
    6,6,6,
    7,7,
    8};
__device__ __constant__ int c_pg[NPAIRS] = {
    1,2,3,4,5,6,7,8,9,
    2,3,4,5,6,7,8,9,
    3,4,5,6,7,8,9,
    4,5,6,7,8,9,
    5,6,7,8,9,
    6,7,8,9,
    7,8,9,
    8,9,
    9};

__global__ __launch_bounds__(256) void ffm_kernel(
    const int* __restrict__ x,       // (B, F) int32
    const float* __restrict__ w,     // (INPUT_DIM,)
    const float* __restrict__ blin,  // scalar
    const float* __restrict__ emb,   // (F, INPUT_DIM, D)
    float* __restrict__ out)         // (B,)
{
    const int gtid = blockIdx.x * blockDim.x + threadIdx.x;
    const int wave = gtid >> 6;
    const int lane = threadIdx.x & 63;

    const int b0 = wave * SPW;
    if (b0 >= BATCH) return;

    const float bl = *blin;

    const int p  = (lane < NPAIRS) ? lane : 0;
    const int pf = c_pf[p];
    const int pg = c_pg[p];
    const int jl = (lane >= NPAIRS && lane < NPAIRS + NUM_FIELDS) ? (lane - NPAIRS) : 0;

    // coalesced: lanes 0..39 read 4 samples' indices in one 160B transaction
    int idx = 0;
    if (lane < SPW * NUM_FIELDS)
        idx = x[b0 * NUM_FIELDS + lane] + c_off40[lane];

    // Issue ALL gathers for 4 samples before any consumption -> 16 loads in flight
    float4 va0[SPW], va1[SPW], vb0[SPW], vb1[SPW];
    float  wv[SPW];
    #pragma unroll
    for (int s = 0; s < SPW; ++s) {
        // broadcasts done unconditionally (source lanes 0..39 hold valid data)
        const int ig = __shfl(idx, s * NUM_FIELDS + pg);  // x_off[b0+s, g]
        const int If = __shfl(idx, s * NUM_FIELDS + pf);  // x_off[b0+s, f]
        const int ij = __shfl(idx, s * NUM_FIELDS + jl);  // x_off[b0+s, lane-45]
        if (lane < NPAIRS) {
            const float4* pa = reinterpret_cast<const float4*>(
                emb + ((size_t)pf * INPUT_DIM + ig) * FACTOR_DIM);
            const float4* pb = reinterpret_cast<const float4*>(
                emb + ((size_t)pg * INPUT_DIM + If) * FACTOR_DIM);
            va0[s] = pa[0]; va1[s] = pa[1];
            vb0[s] = pb[0]; vb1[s] = pb[1];
            wv[s] = 0.0f;
        } else if (lane < NPAIRS + NUM_FIELDS) {
            wv[s] = w[ij];
        } else {
            wv[s] = 0.0f;
        }
    }

    // Consume: dot + full-wave butterfly reduction per sample
    float res[SPW];
    #pragma unroll
    for (int s = 0; s < SPW; ++s) {
        float v;
        if (lane < NPAIRS) {
            v = va0[s].x * vb0[s].x + va0[s].y * vb0[s].y
              + va0[s].z * vb0[s].z + va0[s].w * vb0[s].w
              + va1[s].x * vb1[s].x + va1[s].y * vb1[s].y
              + va1[s].z * vb1[s].z + va1[s].w * vb1[s].w;
        } else {
            v = wv[s];
        }
        #pragma unroll
        for (int m = 1; m < 64; m <<= 1)
            v += __shfl_xor(v, m);
        res[s] = v;
    }

    if (lane == 0) {
        float4 o = make_float4(res[0] + bl, res[1] + bl, res[2] + bl, res[3] + bl);
        *reinterpret_cast<float4*>(out + b0) = o;  // b0 is a multiple of 4 -> 16B aligned
    }
}

extern "C" void kernel_launch(void* const* d_in, const int* in_sizes, int n_in,
                              void* d_out, int out_size, void* d_ws, size_t ws_size,
                              hipStream_t stream) {
    const int*   x    = (const int*)d_in[0];
    const float* w    = (const float*)d_in[1];
    const float* blin = (const float*)d_in[2];
    const float* emb  = (const float*)d_in[3];
    float*       out  = (float*)d_out;

    // 16384 samples / 4 per wave = 4096 waves = 1024 blocks of 256
    dim3 block(256);
    dim3 grid((BATCH / SPW + 3) / 4);
    hipLaunchKernelGGL(ffm_kernel, grid, block, 0, stream, x, w, blin, emb, out);
}

// Round 3
// 103.331 us; speedup vs baseline: 1.0195x; 1.0059x over previous
//
#include <hip/hip_runtime.h>

#define NUM_FIELDS 10
#define FACTOR_DIM 8
#define BATCH      16384
#define INPUT_DIM  188610
#define NITEMS     55   // 45 pair-dots + 10 linear-weight gathers
#define SPW        4    // samples per wave, 16 lanes each

// offsets replicated 4x so lane (s*10+f) gets field f's offset directly
__device__ __constant__ int c_off40[SPW * NUM_FIELDS] = {
    0, 100000, 150000, 170000, 180000, 185000, 187000, 188000, 188500, 188600,
    0, 100000, 150000, 170000, 180000, 185000, 187000, 188000, 188500, 188600,
    0, 100000, 150000, 170000, 180000, 185000, 187000, 188000, 188500, 188600,
    0, 100000, 150000, 170000, 180000, 185000, 187000, 188000, 188500, 188600};

// item i in [0,45): pair (f,g), f-major; item i in [45,55): linear term j=i-45
// tA = table of first vector (-1 => linear item)
// sA = field whose index selects the row of the first vector (or j for linear)
// tB/sB = same for second vector
__device__ __constant__ signed char c_tA[NITEMS] = {
    0,0,0,0,0,0,0,0,0, 1,1,1,1,1,1,1,1, 2,2,2,2,2,2,2, 3,3,3,3,3,3,
    4,4,4,4,4, 5,5,5,5, 6,6,6, 7,7, 8,
    -1,-1,-1,-1,-1,-1,-1,-1,-1,-1};
__device__ __constant__ signed char c_sA[NITEMS] = {
    1,2,3,4,5,6,7,8,9, 2,3,4,5,6,7,8,9, 3,4,5,6,7,8,9, 4,5,6,7,8,9,
    5,6,7,8,9, 6,7,8,9, 7,8,9, 8,9, 9,
    0,1,2,3,4,5,6,7,8,9};
__device__ __constant__ signed char c_tB[NITEMS] = {
    1,2,3,4,5,6,7,8,9, 2,3,4,5,6,7,8,9, 3,4,5,6,7,8,9, 4,5,6,7,8,9,
    5,6,7,8,9, 6,7,8,9, 7,8,9, 8,9, 9,
    0,0,0,0,0,0,0,0,0,0};
__device__ __constant__ signed char c_sB[NITEMS] = {
    0,0,0,0,0,0,0,0,0, 1,1,1,1,1,1,1,1, 2,2,2,2,2,2,2, 3,3,3,3,3,3,
    4,4,4,4,4, 5,5,5,5, 6,6,6, 7,7, 8,
    0,0,0,0,0,0,0,0,0,0};

__global__ __launch_bounds__(256) void ffm_kernel(
    const int* __restrict__ x,       // (B, F) int32
    const float* __restrict__ w,     // (INPUT_DIM,)
    const float* __restrict__ blin,  // scalar
    const float* __restrict__ emb,   // (F, INPUT_DIM, D)
    float* __restrict__ out)         // (B,)
{
    const int wave = (blockIdx.x * blockDim.x + threadIdx.x) >> 6;
    const int lane = threadIdx.x & 63;
    const int grp  = lane >> 4;      // sample slot within wave (0..3)
    const int gl   = lane & 15;      // lane within 16-lane group

    const int b0 = wave * SPW;
    if (b0 >= BATCH) return;

    const float bl = *blin;

    // coalesced: lanes 0..39 read 4 samples' indices (one 160B transaction)
    int idx = 0;
    if (lane < SPW * NUM_FIELDS)
        idx = x[b0 * NUM_FIELDS + lane] + c_off40[lane];

    // Stage ALL loads for this lane's <=4 items before consuming
    float4 a0[4], a1[4], bv0[4], bv1[4];
    float  wv[4];
    bool   ispair[4];
    #pragma unroll
    for (int k = 0; k < 4; ++k) {
        const int it  = gl + 16 * k;            // item id, 0..63
        const bool act = (it < NITEMS);
        const int ii  = act ? it : 0;
        const int tA = c_tA[ii], sA = c_sA[ii];
        const int tB = c_tB[ii], sB = c_sB[ii];
        // broadcasts unconditional; source lanes 0..39 hold valid idx
        const int ia = __shfl(idx, grp * NUM_FIELDS + sA);
        const int ib = __shfl(idx, grp * NUM_FIELDS + sB);
        wv[k] = 0.0f;
        ispair[k] = act && (tA >= 0);
        if (ispair[k]) {
            const float4* pa = reinterpret_cast<const float4*>(
                emb + ((size_t)tA * INPUT_DIM + ia) * FACTOR_DIM);
            const float4* pb = reinterpret_cast<const float4*>(
                emb + ((size_t)tB * INPUT_DIM + ib) * FACTOR_DIM);
            a0[k] = pa[0]; a1[k] = pa[1];
            bv0[k] = pb[0]; bv1[k] = pb[1];
        } else if (act) {
            wv[k] = w[ia];
        }
    }

    // Consume
    float val = 0.0f;
    #pragma unroll
    for (int k = 0; k < 4; ++k) {
        if (ispair[k]) {
            val += a0[k].x * bv0[k].x + a0[k].y * bv0[k].y
                 + a0[k].z * bv0[k].z + a0[k].w * bv0[k].w
                 + a1[k].x * bv1[k].x + a1[k].y * bv1[k].y
                 + a1[k].z * bv1[k].z + a1[k].w * bv1[k].w;
        } else {
            val += wv[k];
        }
    }

    // one shared butterfly over each 16-lane group (serves all 4 samples)
    val += __shfl_xor(val, 1);
    val += __shfl_xor(val, 2);
    val += __shfl_xor(val, 4);
    val += __shfl_xor(val, 8);

    // lanes 0,16,32,48 write consecutive outputs -> coalesced
    if (gl == 0) out[b0 + grp] = val + bl;
}

extern "C" void kernel_launch(void* const* d_in, const int* in_sizes, int n_in,
                              void* d_out, int out_size, void* d_ws, size_t ws_size,
                              hipStream_t stream) {
    const int*   x    = (const int*)d_in[0];
    const float* w    = (const float*)d_in[1];
    const float* blin = (const float*)d_in[2];
    const float* emb  = (const float*)d_in[3];
    float*       out  = (float*)d_out;

    // 16384 samples / 4 per wave = 4096 waves = 1024 blocks of 256
    dim3 block(256);
    dim3 grid(BATCH / SPW / 4);
    hipLaunchKernelGGL(ffm_kernel, grid, block, 0, stream, x, w, blin, emb, out);
}